// Round 8
// baseline (387.910 us; speedup 1.0000x reference)
//
#include <hip/hip_runtime.h>
#include <math.h>

#define B_ 4
#define K_ 4096
#define C_ 256
#define H_ 128
#define RAD 5
#define NB (2 * RAD + 1)
#define PSTRIDE 12     // 11 band weights (+1 pad)
#define WROWS 8        // rows per weighted block
#define FROWS 8        // rows per wfill block

typedef float floatx4 __attribute__((ext_vector_type(4)));

// ws layout (floats):
//   s:        [B_*K_]          @ 0
//   Ssum:     [B_*C_]          @ 16384
//   partial:  [512*C_]         @ 17408
//   params:   [B_*K_*PSTRIDE]  @ 148480
//   woff_arr: [B_*K_]          @ 345088

// ---------------- K1: per-token MLP score ----------------
__global__ __launch_bounds__(128) void score_kernel(
    const float* __restrict__ x, const float* __restrict__ W1,
    const float* __restrict__ b1, const float* __restrict__ W2,
    const float* __restrict__ b2, float* __restrict__ s_out)
{
    const int tid = threadIdx.x;
    const int t0 = blockIdx.x * 8;
    const float* xr[8];
    #pragma unroll
    for (int t = 0; t < 8; ++t) xr[t] = x + (size_t)(t0 + t) * C_;

    float acc[8];
    float binit = b1[tid];
    #pragma unroll
    for (int t = 0; t < 8; ++t) acc[t] = binit;

    for (int c = 0; c < C_; c += 4) {
        float w0 = W1[(c + 0) * H_ + tid];
        float w1 = W1[(c + 1) * H_ + tid];
        float w2 = W1[(c + 2) * H_ + tid];
        float w3 = W1[(c + 3) * H_ + tid];
        #pragma unroll
        for (int t = 0; t < 8; ++t) {
            floatx4 xv = *(const floatx4*)&xr[t][c];   // wave-uniform -> s_load
            acc[t] = fmaf(xv.x, w0, acc[t]);
            acc[t] = fmaf(xv.y, w1, acc[t]);
            acc[t] = fmaf(xv.z, w2, acc[t]);
            acc[t] = fmaf(xv.w, w3, acc[t]);
        }
    }

    __shared__ float red[2][8];
    float w2v = W2[tid];
    #pragma unroll
    for (int t = 0; t < 8; ++t) {
        float p = tanhf(acc[t]) * w2v;
        #pragma unroll
        for (int off = 32; off > 0; off >>= 1) p += __shfl_down(p, off);
        if ((tid & 63) == 0) red[tid >> 6][t] = p;
    }
    __syncthreads();
    if (tid < 8) s_out[t0 + tid] = red[0][tid] + red[1][tid] + b2[0];
}

// ---------------- K2a/K2b: per-batch column sums ----------------
__global__ __launch_bounds__(256) void colsum_partial(
    const float* __restrict__ x, float* __restrict__ partial)
{
    const int tid = threadIdx.x;
    const int blk = blockIdx.x;
    const float* base = x + (size_t)blk * 32 * C_ + tid;
    float a0 = 0.f, a1 = 0.f, a2 = 0.f, a3 = 0.f;
    #pragma unroll
    for (int kk = 0; kk < 32; kk += 4) {
        a0 += base[(size_t)(kk + 0) * C_];
        a1 += base[(size_t)(kk + 1) * C_];
        a2 += base[(size_t)(kk + 2) * C_];
        a3 += base[(size_t)(kk + 3) * C_];
    }
    partial[(size_t)blk * C_ + tid] = (a0 + a1) + (a2 + a3);
}

__global__ __launch_bounds__(1024) void colsum_final(
    const float* __restrict__ partial, float* __restrict__ Ssum)
{
    const int c = threadIdx.x & 255;
    const int g = threadIdx.x >> 8;
    const int b = blockIdx.x;
    __shared__ float red[4][C_];
    float acc = 0.f;
    const float* pb = partial + ((size_t)b * 128 + g * 32) * C_ + c;
    #pragma unroll 4
    for (int ch = 0; ch < 32; ++ch) acc += pb[(size_t)ch * C_];
    red[g][c] = acc;
    __syncthreads();
    if (g == 0) Ssum[b * C_ + c] = red[0][c] + red[1][c] + red[2][c] + red[3][c];
}

// ---------------- K3: softmax params, one THREAD per row ----------------
__global__ __launch_bounds__(256) void params_kernel(
    const float* __restrict__ s, float* __restrict__ params,
    float* __restrict__ woff_arr)
{
    const int row = blockIdx.x * 256 + threadIdx.x;   // b*K_ + i
    const int b = row >> 12;
    const int i = row & (K_ - 1);
    const int j0 = max(0, i - RAD), j1 = min(K_ - 1, i + RAD);
    const int nb = j1 - j0 + 1;
    const float* srow = s + b * K_;

    float sv[NB];
    float m = 0.f;                                    // off-band score 0 => max >= 0
    #pragma unroll
    for (int jj = 0; jj < NB; ++jj) {
        float v = (jj < nb) ? srow[j0 + jj] : 0.f;
        sv[jj] = v;
        if (jj < nb) m = fmaxf(m, v);
    }
    float e0 = expf(-m);
    float D = (float)(K_ - nb) * e0;
    float* pp = params + (size_t)row * PSTRIDE;
    #pragma unroll
    for (int jj = 0; jj < NB; ++jj) {
        float e = expf(sv[jj] - m);
        if (jj < nb) D += e;
        sv[jj] = e;
    }
    float inv = 1.0f / D;
    #pragma unroll
    for (int jj = 0; jj < NB; ++jj) pp[jj] = sv[jj] * inv;  // jj>=nb slots unread
    woff_arr[row] = e0 * inv;
}

// ---------------- K4: weighted rows, 8 rows per block ----------------
__global__ __launch_bounds__(256) void weighted_kernel(
    const float* __restrict__ x, const float* __restrict__ params,
    const float* __restrict__ woff_arr, const float* __restrict__ Ssum,
    float* __restrict__ out)
{
    const int tid = threadIdx.x;
    const int blk = blockIdx.x;                       // b*(K_/WROWS) + tile
    const int b  = blk >> 9;
    const int i0 = (blk & 511) * WROWS;

    const int j0t = max(0, i0 - RAD);
    const int j1t = min(K_ - 1, i0 + WROWS - 1 + RAD);
    const int ntok = j1t - j0t + 1;                   // <= 18

    __shared__ float xs[WROWS + 2 * RAD][C_];         // 18 KB
    __shared__ float prm[WROWS][PSTRIDE];
    __shared__ float wo_s[WROWS];

    if (tid < WROWS * PSTRIDE)
        ((float*)prm)[tid] = params[(size_t)(b * K_ + i0) * PSTRIDE + tid];
    if (tid >= 128 && tid < 128 + WROWS)
        wo_s[tid - 128] = woff_arr[b * K_ + i0 + (tid - 128)];
    const floatx4* xsrc = (const floatx4*)(x + ((size_t)b * K_ + j0t) * C_);
    floatx4* xdst = (floatx4*)&xs[0][0];
    for (int f = tid; f < ntok * (C_ / 4); f += 256) xdst[f] = xsrc[f];
    __syncthreads();

    const float sc = Ssum[b * C_ + tid];
    #pragma unroll
    for (int r = 0; r < WROWS; ++r) {
        const int i = i0 + r;
        const int j0 = max(0, i - RAD), j1 = min(K_ - 1, i + RAD);
        const float wo = wo_s[r];
        float acc = wo * sc;
        for (int j = j0; j <= j1; ++j)
            acc = fmaf(prm[r][j - j0] - wo, xs[j - j0t][tid], acc);
        out[((size_t)b * K_ + i) * C_ + tid] = acc;
    }
}

// ---------------- K5: fill-shaped weights stream ----------------
// Structurally mirrors the 6.4 TB/s harness fill: no LDS, no barrier, tiny
// VGPR count, straight-line dwordx4 stores. Value = wave-uniform woff (s_load;
// row per unrolled step is (k>>2), compile-time uniform) with rare band patch.
__global__ __launch_bounds__(256) void wfill_kernel(
    const float* __restrict__ params, const float* __restrict__ woff_arr,
    float* __restrict__ out)
{
    const int tid = threadIdx.x;
    const int r0 = blockIdx.x * FROWS;                // global row = b*K_ + i
    floatx4* wbase = (floatx4*)(out + (size_t)B_ * K_ * C_) + (size_t)r0 * (K_ / 4);

    #pragma unroll
    for (int m = 0; m < FROWS; ++m) {
        const int rr = r0 + m;
        const int i = rr & (K_ - 1);
        const int j0 = max(0, i - RAD), j1 = min(K_ - 1, i + RAD);
        const float wo = woff_arr[rr];                // uniform -> s_load
        floatx4* wrow = wbase + (size_t)m * (K_ / 4);
        #pragma unroll
        for (int q = 0; q < 4; ++q) {
            const int f = q * 256 + tid;
            const int jb = f * 4;
            floatx4 v = { wo, wo, wo, wo };
            if (jb + 3 >= j0 && jb <= j1) {           // execz-skipped for most waves
                const float* pp = params + (size_t)rr * PSTRIDE;
                if (jb + 0 >= j0 && jb + 0 <= j1) v.x = pp[jb + 0 - j0];
                if (jb + 1 >= j0 && jb + 1 <= j1) v.y = pp[jb + 1 - j0];
                if (jb + 2 >= j0 && jb + 2 <= j1) v.z = pp[jb + 2 - j0];
                if (jb + 3 >= j0 && jb + 3 <= j1) v.w = pp[jb + 3 - j0];
            }
            wrow[f] = v;
        }
    }
}

extern "C" void kernel_launch(void* const* d_in, const int* in_sizes, int n_in,
                              void* d_out, int out_size, void* d_ws, size_t ws_size,
                              hipStream_t stream) {
    const float* x  = (const float*)d_in[0];
    const float* W1 = (const float*)d_in[1];
    const float* b1 = (const float*)d_in[2];
    const float* W2 = (const float*)d_in[3];
    const float* b2 = (const float*)d_in[4];
    float* out = (float*)d_out;

    float* ws       = (float*)d_ws;
    float* s        = ws;                     // 16384
    float* Ssum     = ws + 16384;             // 1024
    float* partial  = ws + 17408;             // 131072
    float* params   = ws + 148480;            // 196608
    float* woff_arr = ws + 345088;            // 16384

    score_kernel   <<<B_ * K_ / 8,     128,  0, stream>>>(x, W1, b1, W2, b2, s);
    colsum_partial <<<B_ * 128,        256,  0, stream>>>(x, partial);
    colsum_final   <<<B_,              1024, 0, stream>>>(partial, Ssum);
    params_kernel  <<<B_ * K_ / 256,   256,  0, stream>>>(s, params, woff_arr);
    weighted_kernel<<<B_ * K_ / WROWS, 256,  0, stream>>>(x, params, woff_arr, Ssum, out);
    wfill_kernel   <<<B_ * K_ / FROWS, 256,  0, stream>>>(params, woff_arr, out);
}

// Round 9
// 381.038 us; speedup vs baseline: 1.0180x; 1.0180x over previous
//
#include <hip/hip_runtime.h>
#include <math.h>

#define B_ 4
#define K_ 4096
#define C_ 256
#define H_ 128
#define RAD 5
#define NB (2 * RAD + 1)
#define ROWS 8          // query rows per output block

typedef float floatx4 __attribute__((ext_vector_type(4)));

// ws layout (floats):
//   s:       [B_*K_]   @ 0
//   Ssum:    [B_*C_]   @ 16384
//   partial: [512*C_]  @ 17408

// ---------------- K1: per-token MLP score ----------------
__global__ __launch_bounds__(128) void score_kernel(
    const float* __restrict__ x, const float* __restrict__ W1,
    const float* __restrict__ b1, const float* __restrict__ W2,
    const float* __restrict__ b2, float* __restrict__ s_out)
{
    const int tid = threadIdx.x;
    const int t0 = blockIdx.x * 8;
    const float* xr[8];
    #pragma unroll
    for (int t = 0; t < 8; ++t) xr[t] = x + (size_t)(t0 + t) * C_;

    float acc[8];
    float binit = b1[tid];
    #pragma unroll
    for (int t = 0; t < 8; ++t) acc[t] = binit;

    for (int c = 0; c < C_; c += 4) {
        float w0 = W1[(c + 0) * H_ + tid];
        float w1 = W1[(c + 1) * H_ + tid];
        float w2 = W1[(c + 2) * H_ + tid];
        float w3 = W1[(c + 3) * H_ + tid];
        #pragma unroll
        for (int t = 0; t < 8; ++t) {
            floatx4 xv = *(const floatx4*)&xr[t][c];   // wave-uniform -> s_load
            acc[t] = fmaf(xv.x, w0, acc[t]);
            acc[t] = fmaf(xv.y, w1, acc[t]);
            acc[t] = fmaf(xv.z, w2, acc[t]);
            acc[t] = fmaf(xv.w, w3, acc[t]);
        }
    }

    __shared__ float red[2][8];
    float w2v = W2[tid];
    #pragma unroll
    for (int t = 0; t < 8; ++t) {
        float p = tanhf(acc[t]) * w2v;
        #pragma unroll
        for (int off = 32; off > 0; off >>= 1) p += __shfl_down(p, off);
        if ((tid & 63) == 0) red[tid >> 6][t] = p;
    }
    __syncthreads();
    if (tid < 8) s_out[t0 + tid] = red[0][tid] + red[1][tid] + b2[0];
}

// ---------------- K2a/K2b: per-batch column sums ----------------
__global__ __launch_bounds__(256) void colsum_partial(
    const float* __restrict__ x, float* __restrict__ partial)
{
    const int tid = threadIdx.x;
    const int blk = blockIdx.x;
    const float* base = x + (size_t)blk * 32 * C_ + tid;
    float a0 = 0.f, a1 = 0.f, a2 = 0.f, a3 = 0.f;
    #pragma unroll
    for (int kk = 0; kk < 32; kk += 4) {
        a0 += base[(size_t)(kk + 0) * C_];
        a1 += base[(size_t)(kk + 1) * C_];
        a2 += base[(size_t)(kk + 2) * C_];
        a3 += base[(size_t)(kk + 3) * C_];
    }
    partial[(size_t)blk * C_ + tid] = (a0 + a1) + (a2 + a3);
}

__global__ __launch_bounds__(1024) void colsum_final(
    const float* __restrict__ partial, float* __restrict__ Ssum)
{
    const int c = threadIdx.x & 255;
    const int g = threadIdx.x >> 8;
    const int b = blockIdx.x;
    __shared__ float red[4][C_];
    float acc = 0.f;
    const float* pb = partial + ((size_t)b * 128 + g * 32) * C_ + c;
    #pragma unroll 4
    for (int ch = 0; ch < 32; ++ch) acc += pb[(size_t)ch * C_];
    red[g][c] = acc;
    __syncthreads();
    if (g == 0) Ssum[b * C_ + c] = red[0][c] + red[1][c] + red[2][c] + red[3][c];
}

// ---------------- K3: fused softmax + weighted + weights stream ----------------
// 2048 blocks x 256 thr, 8 rows each. Head is cheap: 18 s-loads + 8x11 expf
// on threads 0..7. Then 8x256 weighted row (LDS-staged x band) and 8x16KB
// weights stream.
__global__ __launch_bounds__(256) void out_kernel(
    const float* __restrict__ x, const float* __restrict__ s,
    const float* __restrict__ Ssum, float* __restrict__ out)
{
    const int tid = threadIdx.x;
    const int blk = blockIdx.x;                       // b*(K_/ROWS) + tile
    const int b  = blk >> 9;
    const int i0 = (blk & 511) * ROWS;

    const int j0t = max(0, i0 - RAD);
    const int j1t = min(K_ - 1, i0 + ROWS - 1 + RAD);
    const int ntok = j1t - j0t + 1;                   // <= 18

    __shared__ float xs[ROWS + 2 * RAD][C_];          // 18 KB
    __shared__ float sb[ROWS + 2 * RAD];
    __shared__ float wb[ROWS][NB];
    __shared__ float woff[ROWS];

    if (tid < ntok) sb[tid] = s[b * K_ + j0t + tid];
    const floatx4* xsrc = (const floatx4*)(x + ((size_t)b * K_ + j0t) * C_);
    floatx4* xdst = (floatx4*)&xs[0][0];
    for (int f = tid; f < ntok * (C_ / 4); f += 256) xdst[f] = xsrc[f];
    __syncthreads();

    if (tid < ROWS) {
        const int i = i0 + tid;
        const int j0 = max(0, i - RAD), j1 = min(K_ - 1, i + RAD);
        const int nb = j1 - j0 + 1;
        float m = 0.f;                                // off-band score 0 => max >= 0
        for (int j = j0; j <= j1; ++j) m = fmaxf(m, sb[j - j0t]);
        float e0 = expf(-m);
        float D = (float)(K_ - nb) * e0;
        for (int j = j0; j <= j1; ++j) {
            float e = expf(sb[j - j0t] - m);
            wb[tid][j - j0] = e;
            D += e;
        }
        float inv = 1.0f / D;
        for (int jj = 0; jj < nb; ++jj) wb[tid][jj] *= inv;
        woff[tid] = e0 * inv;
    }
    __syncthreads();

    // ---- weighted rows: thread owns channel tid ----
    const float sc = Ssum[b * C_ + tid];
    #pragma unroll
    for (int r = 0; r < ROWS; ++r) {
        const int i = i0 + r;
        const int j0 = max(0, i - RAD), j1 = min(K_ - 1, i + RAD);
        const float wo = woff[r];
        float acc = wo * sc;
        for (int j = j0; j <= j1; ++j)
            acc = fmaf(wb[r][j - j0] - wo, xs[j - j0t][tid], acc);
        out[((size_t)b * K_ + i) * C_ + tid] = acc;
    }

    // ---- weights rows: 8 x 16 KB contiguous streams ----
    float* wbase = out + (size_t)B_ * K_ * C_ + ((size_t)b * K_ + i0) * K_;
    #pragma unroll
    for (int r = 0; r < ROWS; ++r) {
        const int i = i0 + r;
        const int j0 = max(0, i - RAD), j1 = min(K_ - 1, i + RAD);
        const float wo = woff[r];
        floatx4* wrow4 = (floatx4*)(wbase + (size_t)r * K_);
        #pragma unroll
        for (int q = 0; q < 4; ++q) {
            const int f = tid + 256 * q;
            const int jb = f * 4;
            floatx4 v = { wo, wo, wo, wo };
            if (jb + 3 >= j0 && jb <= j1) {           // rare band patch
                if (jb + 0 >= j0 && jb + 0 <= j1) v.x = wb[r][jb + 0 - j0];
                if (jb + 1 >= j0 && jb + 1 <= j1) v.y = wb[r][jb + 1 - j0];
                if (jb + 2 >= j0 && jb + 2 <= j1) v.z = wb[r][jb + 2 - j0];
                if (jb + 3 >= j0 && jb + 3 <= j1) v.w = wb[r][jb + 3 - j0];
            }
            wrow4[f] = v;
        }
    }
}

extern "C" void kernel_launch(void* const* d_in, const int* in_sizes, int n_in,
                              void* d_out, int out_size, void* d_ws, size_t ws_size,
                              hipStream_t stream) {
    const float* x  = (const float*)d_in[0];
    const float* W1 = (const float*)d_in[1];
    const float* b1 = (const float*)d_in[2];
    const float* W2 = (const float*)d_in[3];
    const float* b2 = (const float*)d_in[4];
    float* out = (float*)d_out;

    float* ws      = (float*)d_ws;
    float* s       = ws;                      // 16384
    float* Ssum    = ws + 16384;              // 1024
    float* partial = ws + 17408;              // 131072

    score_kernel  <<<B_ * K_ / 8,    128,  0, stream>>>(x, W1, b1, W2, b2, s);
    colsum_partial<<<B_ * 128,       256,  0, stream>>>(x, partial);
    colsum_final  <<<B_,             1024, 0, stream>>>(partial, Ssum);
    out_kernel    <<<B_ * K_ / ROWS, 256,  0, stream>>>(x, s, Ssum, out);
}